// Round 1
// baseline (806.169 us; speedup 1.0000x reference)
//
#include <hip/hip_runtime.h>
#include <hip/hip_bf16.h>

#define N_NODES 50000
#define NE      800000
#define DIN     128
#define DHID    128
#define DOUT    64
#define BN_EPS  1e-5f

typedef __hip_bfloat16 bf16;

__device__ __forceinline__ float bf2f(bf16 v) { return __bfloat162float(v); }

// Load a float input that may be stored as bf16 or fp32 (uniform flag).
__device__ __forceinline__ float ldf(const void* p, int i, int isbf) {
    if (isbf) return __bfloat162float(((const bf16*)p)[i]);
    return ((const float*)p)[i];
}

// ---------- dtype detection ----------
// flags[0] = 1 if float tensors are bf16; flags[1] = 1 if edge_index is int64
__global__ void k_detect(const unsigned short* W1raw, const unsigned int* eiraw, int* flags) {
    if (threadIdx.x == 0 && blockIdx.x == 0) {
        float mx = 0.f;
        for (int i = 0; i < 256; ++i) {
            unsigned int u = ((unsigned int)W1raw[i]) << 16;
            float f = __uint_as_float(u);
            f = fabsf(f);
            if (!isnan(f) && !isinf(f) && f > mx) mx = f;
        }
        flags[0] = (mx < 1e4f) ? 1 : 0;
        int all0 = 1;
        for (int i = 0; i < 64; ++i)
            if (eiraw[2 * i + 1] != 0u) all0 = 0;
        flags[1] = all0;
    }
}

// ---------- edge index normalize to int32 row/col ----------
__global__ __launch_bounds__(256) void k_edges(const void* eiraw, const int* __restrict__ flags,
                                               int* __restrict__ row, int* __restrict__ col) {
    int e = blockIdx.x * 256 + threadIdx.x;
    if (e >= NE) return;
    if (flags[1]) {
        const long long* p = (const long long*)eiraw;
        row[e] = (int)p[e];
        col[e] = (int)p[NE + e];
    } else {
        const int* p = (const int*)eiraw;
        row[e] = p[e];
        col[e] = p[NE + e];
    }
}

// ---------- degree ----------
__global__ __launch_bounds__(256) void k_deg_init(float* dis) {
    int i = blockIdx.x * 256 + threadIdx.x;
    if (i < N_NODES) dis[i] = 1.0f;   // self loop
}
__global__ __launch_bounds__(256) void k_deg_count(const int* __restrict__ col, float* dis) {
    int e = blockIdx.x * 256 + threadIdx.x;
    if (e < NE) atomicAdd(&dis[col[e]], 1.0f);
}
__global__ __launch_bounds__(256) void k_deg_rsqrt(float* dis) {
    int i = blockIdx.x * 256 + threadIdx.x;
    if (i < N_NODES) dis[i] = rsqrtf(dis[i]);
}

// ---------- GEMM1: h1 = x @ W1 + b1   [N,128]x[128,128] ----------
__global__ __launch_bounds__(128) void k_gemm1(const void* __restrict__ x, const void* __restrict__ W1,
                                               const void* __restrict__ b1, const int* __restrict__ flags,
                                               float* __restrict__ h1) {
    __shared__ float xs[8][DIN];
    int isbf = flags[0];
    int tid = threadIdx.x;
    int row0 = blockIdx.x * 8;
    #pragma unroll
    for (int i = 0; i < 8; ++i)
        xs[i][tid] = ldf(x, (row0 + i) * DIN + tid, isbf);
    __syncthreads();
    float acc[8];
    float bc = ldf(b1, tid, isbf);
    #pragma unroll
    for (int r = 0; r < 8; ++r) acc[r] = bc;
    for (int k = 0; k < DIN; ++k) {
        float w = ldf(W1, k * DHID + tid, isbf);
        #pragma unroll
        for (int r = 0; r < 8; ++r) acc[r] += xs[r][k] * w;
    }
    #pragma unroll
    for (int r = 0; r < 8; ++r) h1[(row0 + r) * DHID + tid] = acc[r];
}

// ---------- propagate (edges only, self loops handled later) ----------
template <int D>
__global__ __launch_bounds__(256) void k_prop(const int* __restrict__ row, const int* __restrict__ col,
                                              const float* __restrict__ dis, const float* __restrict__ h,
                                              float* __restrict__ agg) {
    int t = blockIdx.x * 256 + threadIdx.x;
    int e = t / D;
    int d = t % D;
    if (e >= NE) return;
    int r = row[e], c = col[e];
    float w = dis[r] * dis[c];
    atomicAdd(&agg[c * D + d], w * h[r * D + d]);
}

// ---------- self-loop add + BN statistics ----------
__global__ __launch_bounds__(256) void k_self_stats(const float* __restrict__ h1, const float* __restrict__ dis,
                                                    float* __restrict__ agg1, float* __restrict__ stats) {
    int tid = threadIdx.x;
    const int total = N_NODES * DHID;
    float s = 0.f, s2 = 0.f;
    for (int idx = blockIdx.x * 256 + tid; idx < total; idx += gridDim.x * 256) {
        int node = idx >> 7;
        float dv = dis[node];
        float v = agg1[idx] + dv * dv * h1[idx];
        agg1[idx] = v;
        s += v;
        s2 += v * v;
    }
    __shared__ float ls[256], ls2[256];
    ls[tid] = s; ls2[tid] = s2;
    __syncthreads();
    if (tid < 128) {
        atomicAdd(&stats[tid],        ls[tid] + ls[tid + 128]);
        atomicAdd(&stats[128 + tid], ls2[tid] + ls2[tid + 128]);
    }
}

// ---------- BN finalize: scale/shift per feature ----------
__global__ void k_bn(const float* __restrict__ stats, const void* __restrict__ gamma,
                     const void* __restrict__ beta, const int* __restrict__ flags,
                     float* __restrict__ norm) {
    int d = threadIdx.x;  // 128 threads
    int isbf = flags[0];
    const float invn = 1.0f / (float)N_NODES;
    float mu = stats[d] * invn;
    float var = stats[128 + d] * invn - mu * mu;
    float rs = rsqrtf(var + BN_EPS);
    float g = ldf(gamma, d, isbf);
    norm[d] = rs * g;
    norm[128 + d] = ldf(beta, d, isbf) - mu * rs * g;
}

// ---------- GEMM2 with fused BN+ReLU on input: h2 = relu(bn(agg1)) @ W2 + b2 ----------
__global__ __launch_bounds__(64) void k_gemm2(const float* __restrict__ agg1, const float* __restrict__ norm,
                                              const void* __restrict__ W2, const void* __restrict__ b2,
                                              const int* __restrict__ flags, float* __restrict__ h2) {
    __shared__ float xs[16][DHID];
    __shared__ float sc[DHID], sh[DHID];
    int isbf = flags[0];
    int tid = threadIdx.x;
    int row0 = blockIdx.x * 16;
    sc[tid] = norm[tid];           sc[tid + 64] = norm[tid + 64];
    sh[tid] = norm[128 + tid];     sh[tid + 64] = norm[192 + tid];
    __syncthreads();
    #pragma unroll
    for (int i = 0; i < 32; ++i) {
        int lin = i * 64 + tid;
        int r = lin >> 7, k = lin & 127;
        float v = agg1[(row0 + r) * DHID + k] * sc[k] + sh[k];
        xs[r][k] = v > 0.f ? v : 0.f;
    }
    __syncthreads();
    float acc[16];
    float bc = ldf(b2, tid, isbf);
    #pragma unroll
    for (int r = 0; r < 16; ++r) acc[r] = bc;
    for (int k = 0; k < DHID; ++k) {
        float w = ldf(W2, k * DOUT + tid, isbf);
        #pragma unroll
        for (int r = 0; r < 16; ++r) acc[r] += xs[r][k] * w;
    }
    #pragma unroll
    for (int r = 0; r < 16; ++r) h2[(row0 + r) * DOUT + tid] = acc[r];
}

// ---------- self-loop add + log_softmax, write output ----------
__global__ __launch_bounds__(256) void k_lsm(const float* __restrict__ agg2, const float* __restrict__ h2,
                                             const float* __restrict__ dis, const int* __restrict__ flags,
                                             void* __restrict__ out) {
    int tid = threadIdx.x;
    int lane = tid & 63;
    int rowi = blockIdx.x * 4 + (tid >> 6);
    if (rowi >= N_NODES) return;
    int isbf = flags[0];
    float dv = dis[rowi];
    float v = agg2[rowi * DOUT + lane] + dv * dv * h2[rowi * DOUT + lane];
    float m = v;
    #pragma unroll
    for (int off = 32; off >= 1; off >>= 1) m = fmaxf(m, __shfl_xor(m, off, 64));
    float ex = __expf(v - m);
    float s = ex;
    #pragma unroll
    for (int off = 32; off >= 1; off >>= 1) s += __shfl_xor(s, off, 64);
    float res = v - m - __logf(s);
    if (isbf) ((bf16*)out)[rowi * DOUT + lane] = __float2bfloat16(res);
    else      ((float*)out)[rowi * DOUT + lane] = res;
}

extern "C" void kernel_launch(void* const* d_in, const int* in_sizes, int n_in,
                              void* d_out, int out_size, void* d_ws, size_t ws_size,
                              hipStream_t stream) {
    const void* x     = d_in[0];
    const void* W1    = d_in[1];
    const void* b1    = d_in[2];
    const void* gamma = d_in[3];
    const void* beta  = d_in[4];
    const void* W2    = d_in[5];
    const void* b2    = d_in[6];
    const void* ei    = d_in[7];

    char* w = (char*)d_ws;
    float* agg1  = (float*)(w + 0);           // 25,600,000 B
    float* agg2  = (float*)(w + 25600000);    // 12,800,000 B
    float* stats = (float*)(w + 38400000);    // 1,024 B
    float* norm  = (float*)(w + 38401024);    // 1,024 B
    int*   flags = (int*)  (w + 38402048);    // 128 B
    float* dis   = (float*)(w + 38402176);    // 200,000 B
    float* h1    = (float*)(w + 38602176);    // 25,600,000 B
    float* h2    = (float*)(w + 64202176);    // 12,800,000 B
    int*   row32 = (int*)  (w + 77002176);    // 3,200,000 B
    int*   col32 = (int*)  (w + 80202176);    // 3,200,000 B

    // zero agg1 + agg2 + stats in one shot
    hipMemsetAsync(w, 0, 38401024, stream);

    k_detect<<<1, 64, 0, stream>>>((const unsigned short*)W1, (const unsigned int*)ei, flags);
    k_edges<<<(NE + 255) / 256, 256, 0, stream>>>(ei, flags, row32, col32);

    k_deg_init<<<(N_NODES + 255) / 256, 256, 0, stream>>>(dis);
    k_deg_count<<<(NE + 255) / 256, 256, 0, stream>>>(col32, dis);
    k_deg_rsqrt<<<(N_NODES + 255) / 256, 256, 0, stream>>>(dis);

    k_gemm1<<<N_NODES / 8, 128, 0, stream>>>(x, W1, b1, flags, h1);

    k_prop<DHID><<<(NE * DHID) / 256, 256, 0, stream>>>(row32, col32, dis, h1, agg1);

    k_self_stats<<<512, 256, 0, stream>>>(h1, dis, agg1, stats);
    k_bn<<<1, 128, 0, stream>>>(stats, gamma, beta, flags, norm);

    k_gemm2<<<N_NODES / 16, 64, 0, stream>>>(agg1, norm, W2, b2, flags, h2);

    k_prop<DOUT><<<(NE * DOUT) / 256, 256, 0, stream>>>(row32, col32, dis, h2, agg2);

    k_lsm<<<N_NODES / 4, 256, 0, stream>>>(agg2, h2, dis, flags, d_out);
}

// Round 2
// 448.427 us; speedup vs baseline: 1.7978x; 1.7978x over previous
//
#include <hip/hip_runtime.h>
#include <hip/hip_bf16.h>

#define N_NODES 50000
#define NE      800000
#define DIN     128
#define DHID    128
#define DOUT    64
#define BN_EPS  1e-5f
#define NBLK_SCAN 196   // ceil(50000/256)

typedef __hip_bfloat16 bf16;

// Load a float input that may be stored as bf16 or fp32 (uniform flag).
__device__ __forceinline__ float ldf(const void* p, int i, int isbf) {
    if (isbf) return __bfloat162float(((const bf16*)p)[i]);
    return ((const float*)p)[i];
}

// ---------- dtype detection ----------
// flags[0] = 1 if float tensors are bf16; flags[1] = 1 if edge_index is int64
__global__ void k_detect(const unsigned short* W1raw, const unsigned int* eiraw, int* flags) {
    if (threadIdx.x == 0 && blockIdx.x == 0) {
        float mx = 0.f;
        for (int i = 0; i < 256; ++i) {
            unsigned int u = ((unsigned int)W1raw[i]) << 16;
            float f = __uint_as_float(u);
            f = fabsf(f);
            if (!isnan(f) && !isinf(f) && f > mx) mx = f;
        }
        flags[0] = (mx < 1e4f) ? 1 : 0;
        int all0 = 1;
        for (int i = 0; i < 64; ++i)
            if (eiraw[2 * i + 1] != 0u) all0 = 0;
        flags[1] = all0;
    }
}

// ---------- edge index normalize to int32 row/col ----------
__global__ __launch_bounds__(256) void k_edges(const void* eiraw, const int* __restrict__ flags,
                                               int* __restrict__ row, int* __restrict__ col) {
    int e = blockIdx.x * 256 + threadIdx.x;
    if (e >= NE) return;
    if (flags[1]) {
        const long long* p = (const long long*)eiraw;
        row[e] = (int)p[e];
        col[e] = (int)p[NE + e];
    } else {
        const int* p = (const int*)eiraw;
        row[e] = p[e];
        col[e] = p[NE + e];
    }
}

// ---------- CSR build ----------
__global__ __launch_bounds__(256) void k_count(const int* __restrict__ col, int* __restrict__ counts) {
    int e = blockIdx.x * 256 + threadIdx.x;
    if (e < NE) atomicAdd(&counts[col[e]], 1);
}

// degree = counts + 1 (self loop); dis = deg^-0.5
__global__ __launch_bounds__(256) void k_deg(const int* __restrict__ counts, float* __restrict__ dis) {
    int i = blockIdx.x * 256 + threadIdx.x;
    if (i < N_NODES) dis[i] = rsqrtf((float)(counts[i] + 1));
}

// scan step A: per-256-block sums
__global__ __launch_bounds__(256) void k_scanA(const int* __restrict__ counts, int* __restrict__ bsum) {
    __shared__ int ls[256];
    int i = blockIdx.x * 256 + threadIdx.x;
    ls[threadIdx.x] = (i < N_NODES) ? counts[i] : 0;
    __syncthreads();
    for (int off = 128; off >= 1; off >>= 1) {
        if (threadIdx.x < off) ls[threadIdx.x] += ls[threadIdx.x + off];
        __syncthreads();
    }
    if (threadIdx.x == 0) bsum[blockIdx.x] = ls[0];
}

// scan step B: exclusive scan of block sums (single block, 256 threads)
__global__ __launch_bounds__(256) void k_scanB(const int* __restrict__ bsum, int* __restrict__ boff) {
    __shared__ int ls[256];
    int t = threadIdx.x;
    int v = (t < NBLK_SCAN) ? bsum[t] : 0;
    ls[t] = v;
    __syncthreads();
    for (int off = 1; off < 256; off <<= 1) {
        int add = (t >= off) ? ls[t - off] : 0;
        __syncthreads();
        ls[t] += add;
        __syncthreads();
    }
    if (t < NBLK_SCAN) boff[t] = ls[t] - v;   // exclusive
}

// scan step C: per-block exclusive scan + offset -> start[]
__global__ __launch_bounds__(256) void k_scanC(const int* __restrict__ counts, const int* __restrict__ boff,
                                               int* __restrict__ start) {
    __shared__ int ls[256];
    int t = threadIdx.x;
    int i = blockIdx.x * 256 + t;
    int v = (i < N_NODES) ? counts[i] : 0;
    ls[t] = v;
    __syncthreads();
    for (int off = 1; off < 256; off <<= 1) {
        int add = (t >= off) ? ls[t - off] : 0;
        __syncthreads();
        ls[t] += add;
        __syncthreads();
    }
    if (i < N_NODES) start[i] = boff[blockIdx.x] + ls[t] - v;
    if (i == 0) start[N_NODES] = NE;
}

// fill CSR: ej[pos] = {src_row, weight}
__global__ __launch_bounds__(256) void k_fill(const int* __restrict__ row, const int* __restrict__ col,
                                              const int* __restrict__ start, int* __restrict__ cursor,
                                              const float* __restrict__ dis, int2* __restrict__ ej) {
    int e = blockIdx.x * 256 + threadIdx.x;
    if (e >= NE) return;
    int r = row[e], c = col[e];
    int pos = start[c] + atomicAdd(&cursor[c], 1);
    ej[pos] = make_int2(r, __float_as_int(dis[r] * dis[c]));
}

// ---------- GEMM1: h1 = x @ W1 + b1   [N,128]x[128,128] ----------
__global__ __launch_bounds__(128) void k_gemm1(const void* __restrict__ x, const void* __restrict__ W1,
                                               const void* __restrict__ b1, const int* __restrict__ flags,
                                               float* __restrict__ h1) {
    __shared__ float xs[8][DIN];
    int isbf = flags[0];
    int tid = threadIdx.x;
    int row0 = blockIdx.x * 8;
    #pragma unroll
    for (int i = 0; i < 8; ++i)
        xs[i][tid] = ldf(x, (row0 + i) * DIN + tid, isbf);
    __syncthreads();
    float acc[8];
    float bc = ldf(b1, tid, isbf);
    #pragma unroll
    for (int r = 0; r < 8; ++r) acc[r] = bc;
    for (int k = 0; k < DIN; ++k) {
        float w = ldf(W1, k * DHID + tid, isbf);
        #pragma unroll
        for (int r = 0; r < 8; ++r) acc[r] += xs[r][k] * w;
    }
    #pragma unroll
    for (int r = 0; r < 8; ++r) h1[(row0 + r) * DHID + tid] = acc[r];
}

// ---------- propagate 1 (gather): agg1[n] = dis[n]^2*h1[n] + sum_in w*h1[src] ----------
__global__ __launch_bounds__(128) void k_prop1(const int* __restrict__ start, const int2* __restrict__ ej,
                                               const float* __restrict__ dis, const float* __restrict__ h1,
                                               float* __restrict__ agg1) {
    int n = blockIdx.x;
    int d = threadIdx.x;
    float dv = dis[n];
    float acc = dv * dv * h1[n * DHID + d];
    int s = start[n], t = start[n + 1];
    for (int j = s; j < t; ++j) {
        int2 p = ej[j];
        acc += __int_as_float(p.y) * h1[p.x * DHID + d];
    }
    agg1[n * DHID + d] = acc;
}

// ---------- BN statistics over agg1 ----------
__global__ __launch_bounds__(256) void k_stats(const float* __restrict__ agg1, float* __restrict__ stats) {
    int tid = threadIdx.x;
    const int total = N_NODES * DHID;
    float s = 0.f, s2 = 0.f;
    for (int idx = blockIdx.x * 256 + tid; idx < total; idx += gridDim.x * 256) {
        float v = agg1[idx];
        s += v;
        s2 += v * v;
    }
    __shared__ float ls[256], ls2[256];
    ls[tid] = s; ls2[tid] = s2;
    __syncthreads();
    if (tid < 128) {
        atomicAdd(&stats[tid],        ls[tid] + ls[tid + 128]);
        atomicAdd(&stats[128 + tid], ls2[tid] + ls2[tid + 128]);
    }
}

// ---------- BN finalize: scale/shift per feature ----------
__global__ void k_bn(const float* __restrict__ stats, const void* __restrict__ gamma,
                     const void* __restrict__ beta, const int* __restrict__ flags,
                     float* __restrict__ norm) {
    int d = threadIdx.x;  // 128 threads
    int isbf = flags[0];
    const float invn = 1.0f / (float)N_NODES;
    float mu = stats[d] * invn;
    float var = stats[128 + d] * invn - mu * mu;
    float rs = rsqrtf(var + BN_EPS);
    float g = ldf(gamma, d, isbf);
    norm[d] = rs * g;
    norm[128 + d] = ldf(beta, d, isbf) - mu * rs * g;
}

// ---------- GEMM2 with fused BN+ReLU on input: h2 = relu(bn(agg1)) @ W2 + b2 ----------
__global__ __launch_bounds__(64) void k_gemm2(const float* __restrict__ agg1, const float* __restrict__ norm,
                                              const void* __restrict__ W2, const void* __restrict__ b2,
                                              const int* __restrict__ flags, float* __restrict__ h2) {
    __shared__ float xs[16][DHID];
    __shared__ float sc[DHID], sh[DHID];
    int isbf = flags[0];
    int tid = threadIdx.x;
    int row0 = blockIdx.x * 16;
    sc[tid] = norm[tid];           sc[tid + 64] = norm[tid + 64];
    sh[tid] = norm[128 + tid];     sh[tid + 64] = norm[192 + tid];
    __syncthreads();
    #pragma unroll
    for (int i = 0; i < 32; ++i) {
        int lin = i * 64 + tid;
        int r = lin >> 7, k = lin & 127;
        float v = agg1[(row0 + r) * DHID + k] * sc[k] + sh[k];
        xs[r][k] = v > 0.f ? v : 0.f;
    }
    __syncthreads();
    float acc[16];
    float bc = ldf(b2, tid, isbf);
    #pragma unroll
    for (int r = 0; r < 16; ++r) acc[r] = bc;
    for (int k = 0; k < DHID; ++k) {
        float w = ldf(W2, k * DOUT + tid, isbf);
        #pragma unroll
        for (int r = 0; r < 16; ++r) acc[r] += xs[r][k] * w;
    }
    #pragma unroll
    for (int r = 0; r < 16; ++r) h2[(row0 + r) * DOUT + tid] = acc[r];
}

// ---------- propagate 2 (gather) + log_softmax fused, write output ----------
__global__ __launch_bounds__(64) void k_prop2_lsm(const int* __restrict__ start, const int2* __restrict__ ej,
                                                  const float* __restrict__ dis, const float* __restrict__ h2,
                                                  const int* __restrict__ flags, void* __restrict__ out) {
    int n = blockIdx.x;
    int d = threadIdx.x;
    float dv = dis[n];
    float acc = dv * dv * h2[n * DOUT + d];
    int s = start[n], t = start[n + 1];
    for (int j = s; j < t; ++j) {
        int2 p = ej[j];
        acc += __int_as_float(p.y) * h2[p.x * DOUT + d];
    }
    // log_softmax across the 64 lanes (one wave per node)
    float m = acc;
    #pragma unroll
    for (int off = 32; off >= 1; off >>= 1) m = fmaxf(m, __shfl_xor(m, off, 64));
    float ex = __expf(acc - m);
    float sum = ex;
    #pragma unroll
    for (int off = 32; off >= 1; off >>= 1) sum += __shfl_xor(sum, off, 64);
    float res = acc - m - __logf(sum);
    if (flags[0]) ((bf16*)out)[n * DOUT + d] = __float2bfloat16(res);
    else          ((float*)out)[n * DOUT + d] = res;
}

extern "C" void kernel_launch(void* const* d_in, const int* in_sizes, int n_in,
                              void* d_out, int out_size, void* d_ws, size_t ws_size,
                              hipStream_t stream) {
    const void* x     = d_in[0];
    const void* W1    = d_in[1];
    const void* b1    = d_in[2];
    const void* gamma = d_in[3];
    const void* beta  = d_in[4];
    const void* W2    = d_in[5];
    const void* b2    = d_in[6];
    const void* ei    = d_in[7];

    char* w = (char*)d_ws;
    float* stats  = (float*)(w + 0);          //   1,024 B
    float* norm   = (float*)(w + 1024);       //   1,024 B
    int*   flags  = (int*)  (w + 2048);       //     128 B
    int*   counts = (int*)  (w + 2176);       // 200,000 B
    int*   cursor = (int*)  (w + 202176);     // 200,000 B
    int*   start  = (int*)  (w + 402176);     // 200,016 B (N+1 ints)
    int*   bsum   = (int*)  (w + 602192);     //     784 B -> pad 1024
    int*   boff   = (int*)  (w + 603216);     //     784 B -> pad 1024
    float* dis    = (float*)(w + 604240);     // 200,000 B
    int*   row32  = (int*)  (w + 804240);     // 3,200,000 B
    int*   col32  = (int*)  (w + 4004240);    // 3,200,000 B
    int2*  ej     = (int2*) (w + 7204240);    // 6,400,000 B
    float* h1     = (float*)(w + 13604240);   // 25,600,000 B
    float* agg1   = (float*)(w + 39204240);   // 25,600,000 B
    float* h2     = (float*)(w + 64804240);   // 12,800,000 B
    // total: 77,604,240 B

    // zero stats + counts + cursor (one contiguous memset covers [0, 402176))
    hipMemsetAsync(w, 0, 402176, stream);

    k_detect<<<1, 64, 0, stream>>>((const unsigned short*)W1, (const unsigned int*)ei, flags);
    k_edges<<<(NE + 255) / 256, 256, 0, stream>>>(ei, flags, row32, col32);

    k_count<<<(NE + 255) / 256, 256, 0, stream>>>(col32, counts);
    k_deg<<<(N_NODES + 255) / 256, 256, 0, stream>>>(counts, dis);

    k_scanA<<<NBLK_SCAN, 256, 0, stream>>>(counts, bsum);
    k_scanB<<<1, 256, 0, stream>>>(bsum, boff);
    k_scanC<<<NBLK_SCAN, 256, 0, stream>>>(counts, boff, start);

    k_fill<<<(NE + 255) / 256, 256, 0, stream>>>(row32, col32, start, cursor, dis, ej);

    k_gemm1<<<N_NODES / 8, 128, 0, stream>>>(x, W1, b1, flags, h1);

    k_prop1<<<N_NODES, 128, 0, stream>>>(start, ej, dis, h1, agg1);

    k_stats<<<512, 256, 0, stream>>>(agg1, stats);
    k_bn<<<1, 128, 0, stream>>>(stats, gamma, beta, flags, norm);

    k_gemm2<<<N_NODES / 16, 64, 0, stream>>>(agg1, norm, W2, b2, flags, h2);

    k_prop2_lsm<<<N_NODES, 64, 0, stream>>>(start, ej, dis, h2, flags, d_out);
}

// Round 3
// 407.833 us; speedup vs baseline: 1.9767x; 1.0995x over previous
//
#include <hip/hip_runtime.h>
#include <hip/hip_bf16.h>

#define N_NODES 50000
#define NE      800000
#define DIN     128
#define DHID    128
#define DOUT    64
#define BN_EPS  1e-5f
#define NBLK_SCAN 196   // ceil(50000/256)
#define LDW 136         // padded W1T row length (elements)

typedef __hip_bfloat16 bf16;
typedef short bf16x8 __attribute__((ext_vector_type(8)));
typedef float f32x4 __attribute__((ext_vector_type(4)));

__device__ __forceinline__ float ldf(const void* p, int i, int isbf) {
    if (isbf) return __bfloat162float(((const bf16*)p)[i]);
    return ((const float*)p)[i];
}
__device__ __forceinline__ float b2f(unsigned short u) {
    return __uint_as_float(((unsigned int)u) << 16);
}
__device__ __forceinline__ unsigned short f2b(float f) {
    bf16 h = __float2bfloat16(f);
    return *(unsigned short*)&h;
}

// ---------- dtype detection ----------
__global__ void k_detect(const unsigned short* W1raw, const unsigned int* eiraw, int* flags) {
    if (threadIdx.x == 0 && blockIdx.x == 0) {
        float mx = 0.f;
        for (int i = 0; i < 256; ++i) {
            unsigned int u = ((unsigned int)W1raw[i]) << 16;
            float f = fabsf(__uint_as_float(u));
            if (!isnan(f) && !isinf(f) && f > mx) mx = f;
        }
        flags[0] = (mx < 1e4f) ? 1 : 0;
        int all0 = 1;
        for (int i = 0; i < 64; ++i)
            if (eiraw[2 * i + 1] != 0u) all0 = 0;
        flags[1] = all0;
    }
}

// ---------- edge normalize + per-dest count (fused) ----------
__global__ __launch_bounds__(256) void k_edges(const void* eiraw, const int* __restrict__ flags,
                                               int* __restrict__ row, int* __restrict__ col,
                                               int* __restrict__ counts) {
    int e = blockIdx.x * 256 + threadIdx.x;
    if (e >= NE) return;
    int r, c;
    if (flags[1]) {
        const long long* p = (const long long*)eiraw;
        r = (int)p[e]; c = (int)p[NE + e];
    } else {
        const int* p = (const int*)eiraw;
        r = p[e]; c = p[NE + e];
    }
    row[e] = r; col[e] = c;
    atomicAdd(&counts[c], 1);
}

// ---------- scan step A: block sums (+ fused deg->dis) ----------
__global__ __launch_bounds__(256) void k_scanA(const int* __restrict__ counts, int* __restrict__ bsum,
                                               float* __restrict__ dis) {
    __shared__ int ls[256];
    int i = blockIdx.x * 256 + threadIdx.x;
    int v = (i < N_NODES) ? counts[i] : 0;
    if (i < N_NODES) dis[i] = rsqrtf((float)(v + 1));
    ls[threadIdx.x] = v;
    __syncthreads();
    for (int off = 128; off >= 1; off >>= 1) {
        if (threadIdx.x < off) ls[threadIdx.x] += ls[threadIdx.x + off];
        __syncthreads();
    }
    if (threadIdx.x == 0) bsum[blockIdx.x] = ls[0];
}

__global__ __launch_bounds__(256) void k_scanB(const int* __restrict__ bsum, int* __restrict__ boff) {
    __shared__ int ls[256];
    int t = threadIdx.x;
    int v = (t < NBLK_SCAN) ? bsum[t] : 0;
    ls[t] = v;
    __syncthreads();
    for (int off = 1; off < 256; off <<= 1) {
        int add = (t >= off) ? ls[t - off] : 0;
        __syncthreads();
        ls[t] += add;
        __syncthreads();
    }
    if (t < NBLK_SCAN) boff[t] = ls[t] - v;
}

__global__ __launch_bounds__(256) void k_scanC(const int* __restrict__ counts, const int* __restrict__ boff,
                                               int* __restrict__ start) {
    __shared__ int ls[256];
    int t = threadIdx.x;
    int i = blockIdx.x * 256 + t;
    int v = (i < N_NODES) ? counts[i] : 0;
    ls[t] = v;
    __syncthreads();
    for (int off = 1; off < 256; off <<= 1) {
        int add = (t >= off) ? ls[t - off] : 0;
        __syncthreads();
        ls[t] += add;
        __syncthreads();
    }
    if (i < N_NODES) start[i] = boff[blockIdx.x] + ls[t] - v;
    if (i == 0) start[N_NODES] = NE;
}

__global__ __launch_bounds__(256) void k_fill(const int* __restrict__ row, const int* __restrict__ col,
                                              const int* __restrict__ start, int* __restrict__ cursor,
                                              const float* __restrict__ dis, int2* __restrict__ ej) {
    int e = blockIdx.x * 256 + threadIdx.x;
    if (e >= NE) return;
    int r = row[e], c = col[e];
    int pos = start[c] + atomicAdd(&cursor[c], 1);
    ej[pos] = make_int2(r, __float_as_int(dis[r] * dis[c]));
}

// ---------- GEMM1 (MFMA): h1b = bf16(x @ W1 + b1) ----------
// 4 waves/block, wave w does rows m0=blk*64+w*16, full 128 cols.
__global__ __launch_bounds__(256) void k_gemm1_mfma(const void* __restrict__ x, const void* __restrict__ W1,
                                                    const void* __restrict__ b1, const int* __restrict__ flags,
                                                    unsigned short* __restrict__ h1b) {
    __shared__ unsigned short wt[128 * LDW];   // W1T[n][k] bf16 bits, padded
    int isbf = flags[0];
    int tid = threadIdx.x;
    // stage W1 transposed into LDS
    #pragma unroll 4
    for (int i = 0; i < 64; ++i) {
        int idx = i * 256 + tid;      // over 16384
        int k = idx >> 7, n = idx & 127;
        unsigned short bits;
        if (isbf) bits = ((const unsigned short*)W1)[idx];
        else      bits = f2b(((const float*)W1)[idx]);
        wt[n * LDW + k] = bits;
    }
    __syncthreads();

    int lane = tid & 63;
    int wave = tid >> 6;
    int m0 = blockIdx.x * 64 + wave * 16;
    int lm = lane & 15;           // tile row for A, tile col for C/D
    int quad = lane >> 4;

    // A fragments: 4 k-tiles
    bf16x8 a[4];
    int arow = m0 + lm;
    int arow_c = arow < N_NODES ? arow : 0;
    if (isbf) {
        const unsigned short* xb = (const unsigned short*)x;
        #pragma unroll
        for (int q = 0; q < 4; ++q)
            a[q] = *(const bf16x8*)(xb + arow_c * DIN + q * 32 + quad * 8);
    } else {
        const float* xf = (const float*)x;
        #pragma unroll
        for (int q = 0; q < 4; ++q) {
            bf16x8 t;
            #pragma unroll
            for (int j = 0; j < 8; ++j)
                t[j] = (short)f2b(xf[arow_c * DIN + q * 32 + quad * 8 + j]);
            a[q] = t;
        }
    }

    #pragma unroll
    for (int nt = 0; nt < 8; ++nt) {
        int n0 = nt * 16;
        f32x4 acc = {0.f, 0.f, 0.f, 0.f};
        #pragma unroll
        for (int q = 0; q < 4; ++q) {
            bf16x8 b = *(const bf16x8*)(wt + (n0 + lm) * LDW + q * 32 + quad * 8);
            acc = __builtin_amdgcn_mfma_f32_16x16x32_bf16(a[q], b, acc, 0, 0, 0);
        }
        float bias = ldf(b1, n0 + lm, isbf);
        #pragma unroll
        for (int r = 0; r < 4; ++r) {
            int grow = m0 + quad * 4 + r;
            if (grow < N_NODES)
                h1b[grow * DHID + n0 + lm] = f2b(acc[r] + bias);
        }
    }
}

// ---------- propagate 1 (gather, bf16 source): agg1 fp32 ----------
__global__ __launch_bounds__(128) void k_prop1(const int* __restrict__ start, const int2* __restrict__ ej,
                                               const float* __restrict__ dis,
                                               const unsigned short* __restrict__ h1b,
                                               float* __restrict__ agg1) {
    int n = blockIdx.x;
    int d = threadIdx.x;
    float dv = dis[n];
    float acc = dv * dv * b2f(h1b[n * DHID + d]);
    int s = start[n], t = start[n + 1];
    for (int j = s; j < t; ++j) {
        int2 p = ej[j];
        acc += __int_as_float(p.y) * b2f(h1b[p.x * DHID + d]);
    }
    agg1[n * DHID + d] = acc;
}

// ---------- BN statistics ----------
__global__ __launch_bounds__(256) void k_stats(const float* __restrict__ agg1, float* __restrict__ stats) {
    int tid = threadIdx.x;
    const int total = N_NODES * DHID;
    float s = 0.f, s2 = 0.f;
    for (int idx = blockIdx.x * 256 + tid; idx < total; idx += gridDim.x * 256) {
        float v = agg1[idx];
        s += v; s2 += v * v;
    }
    __shared__ float ls[256], ls2[256];
    ls[tid] = s; ls2[tid] = s2;
    __syncthreads();
    if (tid < 128) {
        atomicAdd(&stats[tid],       ls[tid] + ls[tid + 128]);
        atomicAdd(&stats[128 + tid], ls2[tid] + ls2[tid + 128]);
    }
}

__global__ void k_bn(const float* __restrict__ stats, const void* __restrict__ gamma,
                     const void* __restrict__ beta, const int* __restrict__ flags,
                     float* __restrict__ norm) {
    int d = threadIdx.x;  // 128
    int isbf = flags[0];
    const float invn = 1.0f / (float)N_NODES;
    float mu = stats[d] * invn;
    float var = stats[128 + d] * invn - mu * mu;
    float rs = rsqrtf(var + BN_EPS);
    float g = ldf(gamma, d, isbf);
    norm[d] = rs * g;
    norm[128 + d] = ldf(beta, d, isbf) - mu * rs * g;
}

// ---------- GEMM2 (vector) with fused BN+ReLU, writes bf16 h2b ----------
__global__ __launch_bounds__(64) void k_gemm2(const float* __restrict__ agg1, const float* __restrict__ norm,
                                              const void* __restrict__ W2, const void* __restrict__ b2,
                                              const int* __restrict__ flags, unsigned short* __restrict__ h2b) {
    __shared__ float xs[16][DHID];
    __shared__ float sc[DHID], sh[DHID];
    int isbf = flags[0];
    int tid = threadIdx.x;
    int row0 = blockIdx.x * 16;
    sc[tid] = norm[tid];           sc[tid + 64] = norm[tid + 64];
    sh[tid] = norm[128 + tid];     sh[tid + 64] = norm[192 + tid];
    __syncthreads();
    #pragma unroll
    for (int i = 0; i < 32; ++i) {
        int lin = i * 64 + tid;
        int r = lin >> 7, k = lin & 127;
        float v = agg1[(row0 + r) * DHID + k] * sc[k] + sh[k];
        xs[r][k] = v > 0.f ? v : 0.f;
    }
    __syncthreads();
    float acc[16];
    float bc = ldf(b2, tid, isbf);
    #pragma unroll
    for (int r = 0; r < 16; ++r) acc[r] = bc;
    for (int k = 0; k < DHID; ++k) {
        float w = ldf(W2, k * DOUT + tid, isbf);
        #pragma unroll
        for (int r = 0; r < 16; ++r) acc[r] += xs[r][k] * w;
    }
    #pragma unroll
    for (int r = 0; r < 16; ++r) h2b[(row0 + r) * DOUT + tid] = f2b(acc[r]);
}

// ---------- propagate 2 (gather, bf16) + log_softmax ----------
__global__ __launch_bounds__(64) void k_prop2_lsm(const int* __restrict__ start, const int2* __restrict__ ej,
                                                  const float* __restrict__ dis,
                                                  const unsigned short* __restrict__ h2b,
                                                  const int* __restrict__ flags, void* __restrict__ out) {
    int n = blockIdx.x;
    int d = threadIdx.x;
    float dv = dis[n];
    float acc = dv * dv * b2f(h2b[n * DOUT + d]);
    int s = start[n], t = start[n + 1];
    for (int j = s; j < t; ++j) {
        int2 p = ej[j];
        acc += __int_as_float(p.y) * b2f(h2b[p.x * DOUT + d]);
    }
    float m = acc;
    #pragma unroll
    for (int off = 32; off >= 1; off >>= 1) m = fmaxf(m, __shfl_xor(m, off, 64));
    float ex = __expf(acc - m);
    float sum = ex;
    #pragma unroll
    for (int off = 32; off >= 1; off >>= 1) sum += __shfl_xor(sum, off, 64);
    float res = acc - m - __logf(sum);
    if (flags[0]) ((unsigned short*)out)[n * DOUT + d] = f2b(res);
    else          ((float*)out)[n * DOUT + d] = res;
}

extern "C" void kernel_launch(void* const* d_in, const int* in_sizes, int n_in,
                              void* d_out, int out_size, void* d_ws, size_t ws_size,
                              hipStream_t stream) {
    const void* x     = d_in[0];
    const void* W1    = d_in[1];
    const void* b1    = d_in[2];
    const void* gamma = d_in[3];
    const void* beta  = d_in[4];
    const void* W2    = d_in[5];
    const void* b2    = d_in[6];
    const void* ei    = d_in[7];

    char* w = (char*)d_ws;
    float*          stats  = (float*)(w + 0);          //   1,024
    int*            counts = (int*)  (w + 1024);       // 200,000
    int*            cursor = (int*)  (w + 201024);     // 200,000  -> memset [0,401024)
    float*          norm   = (float*)(w + 401024);     //   1,024
    int*            flags  = (int*)  (w + 402048);     //     128
    int*            start  = (int*)  (w + 402176);     // 200,064
    int*            bsum   = (int*)  (w + 602240);     //   1,024
    int*            boff   = (int*)  (w + 603264);     //   1,024
    float*          dis    = (float*)(w + 604288);     // 200,000
    int*            row32  = (int*)  (w + 804288);     // 3,200,000
    int*            col32  = (int*)  (w + 4004288);    // 3,200,000
    int2*           ej     = (int2*) (w + 7204288);    // 6,400,000
    unsigned short* h1b    = (unsigned short*)(w + 13604288);  // 12,800,000
    float*          agg1   = (float*)(w + 26404288);   // 25,600,000
    unsigned short* h2b    = (unsigned short*)(w + 52004288);  // 6,400,000
    // total ~58.4 MB

    hipMemsetAsync(w, 0, 401024, stream);   // stats + counts + cursor

    k_detect<<<1, 64, 0, stream>>>((const unsigned short*)W1, (const unsigned int*)ei, flags);
    k_edges<<<(NE + 255) / 256, 256, 0, stream>>>(ei, flags, row32, col32, counts);

    k_scanA<<<NBLK_SCAN, 256, 0, stream>>>(counts, bsum, dis);
    k_scanB<<<1, 256, 0, stream>>>(bsum, boff);
    k_scanC<<<NBLK_SCAN, 256, 0, stream>>>(counts, boff, start);
    k_fill<<<(NE + 255) / 256, 256, 0, stream>>>(row32, col32, start, cursor, dis, ej);

    k_gemm1_mfma<<<(N_NODES + 63) / 64, 256, 0, stream>>>(x, W1, b1, flags, h1b);

    k_prop1<<<N_NODES, 128, 0, stream>>>(start, ej, dis, h1b, agg1);

    k_stats<<<512, 256, 0, stream>>>(agg1, stats);
    k_bn<<<1, 128, 0, stream>>>(stats, gamma, beta, flags, norm);

    k_gemm2<<<N_NODES / 16, 64, 0, stream>>>(agg1, norm, W2, b2, flags, h2b);

    k_prop2_lsm<<<N_NODES, 64, 0, stream>>>(start, ej, dis, h2b, flags, d_out);
}

// Round 4
// 317.709 us; speedup vs baseline: 2.5374x; 1.2837x over previous
//
#include <hip/hip_runtime.h>
#include <hip/hip_bf16.h>

#define N_NODES 50000
#define NE      800000
#define DIN     128
#define DHID    128
#define DOUT    64
#define BN_EPS  1e-5f
#define NBLK_SCAN 196   // ceil(50000/256)
#define LDW 136         // padded W1T row length (elements)
#define LDW2 136        // padded W2T row length

typedef __hip_bfloat16 bf16;
typedef short bf16x8 __attribute__((ext_vector_type(8)));
typedef float f32x4 __attribute__((ext_vector_type(4)));

__device__ __forceinline__ float ldf(const void* p, int i, int isbf) {
    if (isbf) return __bfloat162float(((const bf16*)p)[i]);
    return ((const float*)p)[i];
}
__device__ __forceinline__ float b2f(unsigned short u) {
    return __uint_as_float(((unsigned int)u) << 16);
}
__device__ __forceinline__ unsigned short f2b(float f) {
    bf16 h = __float2bfloat16(f);
    return *(unsigned short*)&h;
}
__device__ __forceinline__ float2 up2(unsigned int u) {
    return make_float2(__uint_as_float(u << 16), __uint_as_float(u & 0xffff0000u));
}
__device__ __forceinline__ unsigned int pk2(float a, float b) {
    return ((unsigned int)f2b(a)) | (((unsigned int)f2b(b)) << 16);
}

// ---------- dtype detection ----------
__global__ void k_detect(const unsigned short* W1raw, const unsigned int* eiraw, int* flags) {
    if (threadIdx.x == 0 && blockIdx.x == 0) {
        float mx = 0.f;
        for (int i = 0; i < 256; ++i) {
            unsigned int u = ((unsigned int)W1raw[i]) << 16;
            float f = fabsf(__uint_as_float(u));
            if (!isnan(f) && !isinf(f) && f > mx) mx = f;
        }
        flags[0] = (mx < 1e4f) ? 1 : 0;
        int all0 = 1;
        for (int i = 0; i < 64; ++i)
            if (eiraw[2 * i + 1] != 0u) all0 = 0;
        flags[1] = all0;
    }
}

// ---------- edge normalize + per-dest count (fused) ----------
__global__ __launch_bounds__(256) void k_edges(const void* eiraw, const int* __restrict__ flags,
                                               int* __restrict__ row, int* __restrict__ col,
                                               int* __restrict__ counts) {
    int e = blockIdx.x * 256 + threadIdx.x;
    if (e >= NE) return;
    int r, c;
    if (flags[1]) {
        const long long* p = (const long long*)eiraw;
        r = (int)p[e]; c = (int)p[NE + e];
    } else {
        const int* p = (const int*)eiraw;
        r = p[e]; c = p[NE + e];
    }
    row[e] = r; col[e] = c;
    atomicAdd(&counts[c], 1);
}

// ---------- scan step A: block sums (+ fused deg->dis) ----------
__global__ __launch_bounds__(256) void k_scanA(const int* __restrict__ counts, int* __restrict__ bsum,
                                               float* __restrict__ dis) {
    __shared__ int ls[256];
    int i = blockIdx.x * 256 + threadIdx.x;
    int v = (i < N_NODES) ? counts[i] : 0;
    if (i < N_NODES) dis[i] = rsqrtf((float)(v + 1));
    ls[threadIdx.x] = v;
    __syncthreads();
    for (int off = 128; off >= 1; off >>= 1) {
        if (threadIdx.x < off) ls[threadIdx.x] += ls[threadIdx.x + off];
        __syncthreads();
    }
    if (threadIdx.x == 0) bsum[blockIdx.x] = ls[0];
}

__global__ __launch_bounds__(256) void k_scanB(const int* __restrict__ bsum, int* __restrict__ boff) {
    __shared__ int ls[256];
    int t = threadIdx.x;
    int v = (t < NBLK_SCAN) ? bsum[t] : 0;
    ls[t] = v;
    __syncthreads();
    for (int off = 1; off < 256; off <<= 1) {
        int add = (t >= off) ? ls[t - off] : 0;
        __syncthreads();
        ls[t] += add;
        __syncthreads();
    }
    if (t < NBLK_SCAN) boff[t] = ls[t] - v;
}

__global__ __launch_bounds__(256) void k_scanC(const int* __restrict__ counts, const int* __restrict__ boff,
                                               int* __restrict__ start) {
    __shared__ int ls[256];
    int t = threadIdx.x;
    int i = blockIdx.x * 256 + t;
    int v = (i < N_NODES) ? counts[i] : 0;
    ls[t] = v;
    __syncthreads();
    for (int off = 1; off < 256; off <<= 1) {
        int add = (t >= off) ? ls[t - off] : 0;
        __syncthreads();
        ls[t] += add;
        __syncthreads();
    }
    if (i < N_NODES) start[i] = boff[blockIdx.x] + ls[t] - v;
    if (i == 0) start[N_NODES] = NE;
}

__global__ __launch_bounds__(256) void k_fill(const int* __restrict__ row, const int* __restrict__ col,
                                              const int* __restrict__ start, int* __restrict__ cursor,
                                              const float* __restrict__ dis, int2* __restrict__ ej) {
    int e = blockIdx.x * 256 + threadIdx.x;
    if (e >= NE) return;
    int r = row[e], c = col[e];
    int pos = start[c] + atomicAdd(&cursor[c], 1);
    ej[pos] = make_int2(r, __float_as_int(dis[r] * dis[c]));
}

// ---------- GEMM1 (MFMA): h1b = bf16(x @ W1 + b1) ----------
__global__ __launch_bounds__(256) void k_gemm1_mfma(const void* __restrict__ x, const void* __restrict__ W1,
                                                    const void* __restrict__ b1, const int* __restrict__ flags,
                                                    unsigned short* __restrict__ h1b) {
    __shared__ unsigned short wt[128 * LDW];   // W1T[n][k]
    int isbf = flags[0];
    int tid = threadIdx.x;
    #pragma unroll 4
    for (int i = 0; i < 64; ++i) {
        int idx = i * 256 + tid;      // 16384
        int k = idx >> 7, n = idx & 127;
        unsigned short bits;
        if (isbf) bits = ((const unsigned short*)W1)[idx];
        else      bits = f2b(((const float*)W1)[idx]);
        wt[n * LDW + k] = bits;
    }
    __syncthreads();

    int lane = tid & 63;
    int wave = tid >> 6;
    int m0 = blockIdx.x * 64 + wave * 16;
    int lm = lane & 15;
    int quad = lane >> 4;

    bf16x8 a[4];
    int arow = m0 + lm;
    int arow_c = arow < N_NODES ? arow : 0;
    if (isbf) {
        const unsigned short* xb = (const unsigned short*)x;
        #pragma unroll
        for (int q = 0; q < 4; ++q)
            a[q] = *(const bf16x8*)(xb + arow_c * DIN + q * 32 + quad * 8);
    } else {
        const float* xf = (const float*)x;
        #pragma unroll
        for (int q = 0; q < 4; ++q) {
            bf16x8 t;
            #pragma unroll
            for (int j = 0; j < 8; ++j)
                t[j] = (short)f2b(xf[arow_c * DIN + q * 32 + quad * 8 + j]);
            a[q] = t;
        }
    }

    #pragma unroll
    for (int nt = 0; nt < 8; ++nt) {
        int n0 = nt * 16;
        f32x4 acc = {0.f, 0.f, 0.f, 0.f};
        #pragma unroll
        for (int q = 0; q < 4; ++q) {
            bf16x8 b = *(const bf16x8*)(wt + (n0 + lm) * LDW + q * 32 + quad * 8);
            acc = __builtin_amdgcn_mfma_f32_16x16x32_bf16(a[q], b, acc, 0, 0, 0);
        }
        float bias = ldf(b1, n0 + lm, isbf);
        #pragma unroll
        for (int r = 0; r < 4; ++r) {
            int grow = m0 + quad * 4 + r;
            if (grow < N_NODES)
                h1b[grow * DHID + n0 + lm] = f2b(acc[r] + bias);
        }
    }
}

// ---------- propagate 1: wave per node, 2 feats/lane, 4-edge ILP ----------
__global__ __launch_bounds__(256) void k_prop1(const int* __restrict__ start, const int2* __restrict__ ej,
                                               const float* __restrict__ dis,
                                               const unsigned int* __restrict__ h1p,   // [N][64] dwords
                                               unsigned int* __restrict__ agg1p) {
    int tid = threadIdx.x;
    int n = blockIdx.x * 4 + (tid >> 6);
    if (n >= N_NODES) return;
    int lane = tid & 63;
    float dv = dis[n];
    float2 v = up2(h1p[(size_t)n * 64 + lane]);
    float ax = dv * dv * v.x, ay = dv * dv * v.y;
    int s = start[n], t = start[n + 1];
    int j = s;
    for (; j + 4 <= t; j += 4) {
        int2 p0 = ej[j], p1 = ej[j + 1], p2 = ej[j + 2], p3 = ej[j + 3];
        unsigned int g0 = h1p[(size_t)p0.x * 64 + lane];
        unsigned int g1 = h1p[(size_t)p1.x * 64 + lane];
        unsigned int g2 = h1p[(size_t)p2.x * 64 + lane];
        unsigned int g3 = h1p[(size_t)p3.x * 64 + lane];
        float w0 = __int_as_float(p0.y), w1 = __int_as_float(p1.y);
        float w2 = __int_as_float(p2.y), w3 = __int_as_float(p3.y);
        float2 f0 = up2(g0), f1 = up2(g1), f2 = up2(g2), f3 = up2(g3);
        ax += w0 * f0.x + w1 * f1.x + w2 * f2.x + w3 * f3.x;
        ay += w0 * f0.y + w1 * f1.y + w2 * f2.y + w3 * f3.y;
    }
    for (; j < t; ++j) {
        int2 p = ej[j];
        float w = __int_as_float(p.y);
        float2 f = up2(h1p[(size_t)p.x * 64 + lane]);
        ax += w * f.x; ay += w * f.y;
    }
    agg1p[(size_t)n * 64 + lane] = pk2(ax, ay);
}

// ---------- BN statistics over bf16 agg1 ----------
__global__ __launch_bounds__(256) void k_stats(const unsigned int* __restrict__ agg1p, float* __restrict__ stats) {
    int tid = threadIdx.x;
    const int total = N_NODES * 64;   // dwords
    float sx = 0.f, sy = 0.f, qx = 0.f, qy = 0.f;
    for (int idx = blockIdx.x * 256 + tid; idx < total; idx += gridDim.x * 256) {
        float2 v = up2(agg1p[idx]);
        sx += v.x; sy += v.y; qx += v.x * v.x; qy += v.y * v.y;
    }
    __shared__ float lsx[256], lsy[256], lqx[256], lqy[256];
    lsx[tid] = sx; lsy[tid] = sy; lqx[tid] = qx; lqy[tid] = qy;
    __syncthreads();
    if (tid < 64) {
        float tsx = lsx[tid] + lsx[tid + 64] + lsx[tid + 128] + lsx[tid + 192];
        float tsy = lsy[tid] + lsy[tid + 64] + lsy[tid + 128] + lsy[tid + 192];
        float tqx = lqx[tid] + lqx[tid + 64] + lqx[tid + 128] + lqx[tid + 192];
        float tqy = lqy[tid] + lqy[tid + 64] + lqy[tid + 128] + lqy[tid + 192];
        atomicAdd(&stats[2 * tid], tsx);
        atomicAdd(&stats[2 * tid + 1], tsy);
        atomicAdd(&stats[128 + 2 * tid], tqx);
        atomicAdd(&stats[128 + 2 * tid + 1], tqy);
    }
}

__global__ void k_bn(const float* __restrict__ stats, const void* __restrict__ gamma,
                     const void* __restrict__ beta, const int* __restrict__ flags,
                     float* __restrict__ norm) {
    int d = threadIdx.x;  // 128
    int isbf = flags[0];
    const float invn = 1.0f / (float)N_NODES;
    float mu = stats[d] * invn;
    float var = stats[128 + d] * invn - mu * mu;
    float rs = rsqrtf(var + BN_EPS);
    float g = ldf(gamma, d, isbf);
    norm[d] = rs * g;
    norm[128 + d] = ldf(beta, d, isbf) - mu * rs * g;
}

// ---------- GEMM2 (MFMA) with fused BN+ReLU: h2b = bf16(relu(bn(agg1)) @ W2 + b2) ----------
__global__ __launch_bounds__(256) void k_gemm2_mfma(const unsigned int* __restrict__ agg1p,
                                                    const float* __restrict__ norm,
                                                    const void* __restrict__ W2, const void* __restrict__ b2,
                                                    const int* __restrict__ flags,
                                                    unsigned short* __restrict__ h2b) {
    __shared__ unsigned short w2t[64 * LDW2];   // W2T[n][k]
    __shared__ float sc[128], sh[128];
    int isbf = flags[0];
    int tid = threadIdx.x;
    #pragma unroll 4
    for (int i = 0; i < 32; ++i) {
        int idx = i * 256 + tid;      // 8192
        int k = idx >> 6, n = idx & 63;
        unsigned short bits;
        if (isbf) bits = ((const unsigned short*)W2)[idx];
        else      bits = f2b(((const float*)W2)[idx]);
        w2t[n * LDW2 + k] = bits;
    }
    if (tid < 128) { sc[tid] = norm[tid]; sh[tid] = norm[128 + tid]; }
    __syncthreads();

    int lane = tid & 63;
    int wave = tid >> 6;
    int m0 = blockIdx.x * 64 + wave * 16;
    int lm = lane & 15;
    int quad = lane >> 4;

    int arow = m0 + lm;
    int arow_c = arow < N_NODES ? arow : 0;
    bf16x8 a[4];
    #pragma unroll
    for (int q = 0; q < 4; ++q) {
        uint4 gv = *(const uint4*)(agg1p + (size_t)arow_c * 64 + q * 16 + quad * 4);
        int kb = q * 32 + quad * 8;
        float2 f0 = up2(gv.x), f1 = up2(gv.y), f2 = up2(gv.z), f3 = up2(gv.w);
        float e0 = f0.x * sc[kb + 0] + sh[kb + 0];
        float e1 = f0.y * sc[kb + 1] + sh[kb + 1];
        float e2 = f1.x * sc[kb + 2] + sh[kb + 2];
        float e3 = f1.y * sc[kb + 3] + sh[kb + 3];
        float e4 = f2.x * sc[kb + 4] + sh[kb + 4];
        float e5 = f2.y * sc[kb + 5] + sh[kb + 5];
        float e6 = f3.x * sc[kb + 6] + sh[kb + 6];
        float e7 = f3.y * sc[kb + 7] + sh[kb + 7];
        bf16x8 t;
        t[0] = (short)f2b(e0 > 0.f ? e0 : 0.f);
        t[1] = (short)f2b(e1 > 0.f ? e1 : 0.f);
        t[2] = (short)f2b(e2 > 0.f ? e2 : 0.f);
        t[3] = (short)f2b(e3 > 0.f ? e3 : 0.f);
        t[4] = (short)f2b(e4 > 0.f ? e4 : 0.f);
        t[5] = (short)f2b(e5 > 0.f ? e5 : 0.f);
        t[6] = (short)f2b(e6 > 0.f ? e6 : 0.f);
        t[7] = (short)f2b(e7 > 0.f ? e7 : 0.f);
        a[q] = t;
    }

    #pragma unroll
    for (int nt = 0; nt < 4; ++nt) {
        int n0 = nt * 16;
        f32x4 acc = {0.f, 0.f, 0.f, 0.f};
        #pragma unroll
        for (int q = 0; q < 4; ++q) {
            bf16x8 b = *(const bf16x8*)(w2t + (n0 + lm) * LDW2 + q * 32 + quad * 8);
            acc = __builtin_amdgcn_mfma_f32_16x16x32_bf16(a[q], b, acc, 0, 0, 0);
        }
        float bias = ldf(b2, n0 + lm, isbf);
        #pragma unroll
        for (int r = 0; r < 4; ++r) {
            int grow = m0 + quad * 4 + r;
            if (grow < N_NODES)
                h2b[grow * DOUT + n0 + lm] = f2b(acc[r] + bias);
        }
    }
}

// ---------- propagate 2 + log_softmax: 32 lanes/node, 2 feats/lane, 4-edge ILP ----------
__global__ __launch_bounds__(256) void k_prop2_lsm(const int* __restrict__ start, const int2* __restrict__ ej,
                                                   const float* __restrict__ dis,
                                                   const unsigned int* __restrict__ h2p,   // [N][32] dwords
                                                   const int* __restrict__ flags, void* __restrict__ out) {
    int tid = threadIdx.x;
    int n = blockIdx.x * 8 + (tid >> 5);
    if (n >= N_NODES) return;
    int lane = tid & 31;
    float dv = dis[n];
    float2 v = up2(h2p[(size_t)n * 32 + lane]);
    float ax = dv * dv * v.x, ay = dv * dv * v.y;
    int s = start[n], t = start[n + 1];
    int j = s;
    for (; j + 4 <= t; j += 4) {
        int2 p0 = ej[j], p1 = ej[j + 1], p2 = ej[j + 2], p3 = ej[j + 3];
        unsigned int g0 = h2p[(size_t)p0.x * 32 + lane];
        unsigned int g1 = h2p[(size_t)p1.x * 32 + lane];
        unsigned int g2 = h2p[(size_t)p2.x * 32 + lane];
        unsigned int g3 = h2p[(size_t)p3.x * 32 + lane];
        float w0 = __int_as_float(p0.y), w1 = __int_as_float(p1.y);
        float w2 = __int_as_float(p2.y), w3 = __int_as_float(p3.y);
        float2 f0 = up2(g0), f1 = up2(g1), f2 = up2(g2), f3 = up2(g3);
        ax += w0 * f0.x + w1 * f1.x + w2 * f2.x + w3 * f3.x;
        ay += w0 * f0.y + w1 * f1.y + w2 * f2.y + w3 * f3.y;
    }
    for (; j < t; ++j) {
        int2 p = ej[j];
        float w = __int_as_float(p.y);
        float2 f = up2(h2p[(size_t)p.x * 32 + lane]);
        ax += w * f.x; ay += w * f.y;
    }
    // log_softmax over 64 features held as 2/lane across 32 lanes
    float m = fmaxf(ax, ay);
    #pragma unroll
    for (int off = 16; off >= 1; off >>= 1) m = fmaxf(m, __shfl_xor(m, off, 32));
    float sum = __expf(ax - m) + __expf(ay - m);
    #pragma unroll
    for (int off = 16; off >= 1; off >>= 1) sum += __shfl_xor(sum, off, 32);
    float lse = m + __logf(sum);
    float rx = ax - lse, ry = ay - lse;
    if (flags[0]) {
        ((unsigned int*)out)[(size_t)n * 32 + lane] = pk2(rx, ry);
    } else {
        float2* o = (float2*)((float*)out + (size_t)n * 64 + 2 * lane);
        *o = make_float2(rx, ry);
    }
}

extern "C" void kernel_launch(void* const* d_in, const int* in_sizes, int n_in,
                              void* d_out, int out_size, void* d_ws, size_t ws_size,
                              hipStream_t stream) {
    const void* x     = d_in[0];
    const void* W1    = d_in[1];
    const void* b1    = d_in[2];
    const void* gamma = d_in[3];
    const void* beta  = d_in[4];
    const void* W2    = d_in[5];
    const void* b2    = d_in[6];
    const void* ei    = d_in[7];

    char* w = (char*)d_ws;
    float*          stats  = (float*)(w + 0);          //   1,024
    int*            counts = (int*)  (w + 1024);       // 200,000
    int*            cursor = (int*)  (w + 201024);     // 200,000  (memset [0,401024))
    float*          norm   = (float*)(w + 401024);     //   1,024
    int*            flags  = (int*)  (w + 402048);     //     128
    int*            start  = (int*)  (w + 402176);     // 200,064
    int*            bsum   = (int*)  (w + 602240);     //   1,024
    int*            boff   = (int*)  (w + 603264);     //   1,024
    float*          dis    = (float*)(w + 604288);     // 200,000
    int*            row32  = (int*)  (w + 804288);     // 3,200,000
    int*            col32  = (int*)  (w + 4004288);    // 3,200,000
    int2*           ej     = (int2*) (w + 7204288);    // 6,400,000
    unsigned short* h1b    = (unsigned short*)(w + 13604288);  // 12,800,000
    unsigned int*   agg1p  = (unsigned int*)  (w + 26404288);  // 12,800,000
    unsigned short* h2b    = (unsigned short*)(w + 39204288);  //  6,400,000
    // total ~45.6 MB

    hipMemsetAsync(w, 0, 401024, stream);   // stats + counts + cursor

    k_detect<<<1, 64, 0, stream>>>((const unsigned short*)W1, (const unsigned int*)ei, flags);
    k_edges<<<(NE + 255) / 256, 256, 0, stream>>>(ei, flags, row32, col32, counts);

    k_scanA<<<NBLK_SCAN, 256, 0, stream>>>(counts, bsum, dis);
    k_scanB<<<1, 256, 0, stream>>>(bsum, boff);
    k_scanC<<<NBLK_SCAN, 256, 0, stream>>>(counts, boff, start);
    k_fill<<<(NE + 255) / 256, 256, 0, stream>>>(row32, col32, start, cursor, dis, ej);

    k_gemm1_mfma<<<(N_NODES + 63) / 64, 256, 0, stream>>>(x, W1, b1, flags, h1b);

    k_prop1<<<(N_NODES + 3) / 4, 256, 0, stream>>>(start, ej, dis, (const unsigned int*)h1b, agg1p);

    k_stats<<<256, 256, 0, stream>>>(agg1p, stats);
    k_bn<<<1, 128, 0, stream>>>(stats, gamma, beta, flags, norm);

    k_gemm2_mfma<<<(N_NODES + 63) / 64, 256, 0, stream>>>(agg1p, norm, W2, b2, flags, h2b);

    k_prop2_lsm<<<(N_NODES + 7) / 8, 256, 0, stream>>>(start, ej, dis, (const unsigned int*)h2b, flags, d_out);
}